// Round 9
// baseline (390.989 us; speedup 1.0000x reference)
//
#include <hip/hip_runtime.h>

// ModulatedConv2d: B=16, C=512->512, 3x3 SAME, per-sample demodulated weights.
// R8 = R7 with the A-slab K-depth halved (K=32): phase = (icb64, half, kx),
// sA3 = 3 taps x 128o x 32ch = 24.6KB. LDS 53.2KB -> 3 blocks/CU (12 waves,
// was 8) at UNCHANGED read counts/ratios - pure occupancy/TLP win (R1/R4
// lesson: TLP beats source pipelining for drain hiding). A chunk swizzle for
// 4-chunk rows: j ^ ((row>>1)&3) -> 2-way bank aliasing (free). All R7
// verified pieces kept: sX [px][64ch]+XOR, bfr indexing, ky-reuse, epilogue.

typedef __bf16 bf16x8 __attribute__((ext_vector_type(8)));
typedef float f32x4 __attribute__((ext_vector_type(4)));

__device__ __forceinline__ void async16(const void* g, void* s) {
  __builtin_amdgcn_global_load_lds((const __attribute__((address_space(1))) void*)g,
                                   (__attribute__((address_space(3))) void*)s, 16, 0, 0);
}

// style[b][i] = dot(w_embs[b,:], style_W[i,:]) + style_b[i] + 1
__global__ __launch_bounds__(256) void k_style(const float* __restrict__ we,
                                               const float* __restrict__ sW,
                                               const float* __restrict__ sb,
                                               float* __restrict__ style) {
  int lane = threadIdx.x & 63, wid = threadIdx.x >> 6;
  int b = blockIdx.x >> 7;
  int i = ((blockIdx.x & 127) << 2) + wid;
  const float* wer = we + b * 512;
  const float* swr = sW + i * 512;
  float acc = 0.f;
  for (int d = lane; d < 512; d += 64) acc += wer[d] * swr[d];
#pragma unroll
  for (int off = 32; off; off >>= 1) acc += __shfl_xor(acc, off);
  if (lane == 0) style[b * 512 + i] = acc + sb[i] + 1.0f;
}

// wsq[o][i] = sum_k cw[o][i][k]^2
__global__ __launch_bounds__(256) void k_wsq(const float* __restrict__ cw,
                                             float* __restrict__ wsq) {
  int t = blockIdx.x * 256 + threadIdx.x;  // o*512+i
  const float* p = cw + (long)t * 9;
  float s = 0.f;
#pragma unroll
  for (int k = 0; k < 9; ++k) s += p[k] * p[k];
  wsq[t] = s;
}

// rnorm[b][o] = rsqrt(sum_i style[b,i]^2 * wsq[o,i])
__global__ __launch_bounds__(256) void k_rnorm(const float* __restrict__ style,
                                               const float* __restrict__ wsq,
                                               float* __restrict__ rnorm) {
  int lane = threadIdx.x & 63, wid = threadIdx.x >> 6;
  int idx = blockIdx.x * 4 + wid;  // b*512 + o
  int b = idx >> 9, o = idx & 511;
  float acc = 0.f;
  for (int i = lane; i < 512; i += 64) {
    float s = style[(b << 9) + i];
    acc += s * s * wsq[(o << 9) + i];
  }
#pragma unroll
  for (int off = 32; off; off >>= 1) acc += __shfl_xor(acc, off);
  if (lane == 0) rnorm[idx] = rsqrtf(acc);
}

// wt[b][t'][o][i], t' = kx*3 + ky (kx-MAJOR so a (ky=0..2,kx) slab is
// contiguous): value = cw[o][i][ky*3+kx] * style[b][i] * rnorm[b][o].
__global__ __launch_bounds__(256) void k_wt(const float* __restrict__ cw,
                                            const float* __restrict__ style,
                                            const float* __restrict__ rnorm,
                                            __bf16* __restrict__ wt) {
  int t = blockIdx.x * 256 + threadIdx.x;  // b*262144 + o*512 + i
  int b = t >> 18;
  int oi = t & 262143;
  int o = oi >> 9, i = oi & 511;
  float sc = style[(b << 9) + i] * rnorm[(b << 9) + o];
  const float* p = cw + (long)oi * 9;
#pragma unroll
  for (int k = 0; k < 9; ++k) {  // k = ky*3+kx  ->  t' = kx*3+ky
    int tp = (k % 3) * 3 + k / 3;
    wt[((long)(b * 9 + tp) << 18) + ((long)o << 9) + i] = (__bf16)(p[k] * sc);
  }
}

// xpad[b][r][c][i] (r,c in [0,66)) = bf16(imgs[b][i][r-1][c-1]), zero border.
__global__ __launch_bounds__(256) void k_xpad(const float* __restrict__ imgs,
                                              __bf16* __restrict__ xpad) {
  int t = blockIdx.x * 256 + threadIdx.x;  // b*4356 + r*66 + c
  if (t >= 16 * 4356) return;
  int b = t / 4356;
  int rc = t - b * 4356;
  int r = rc / 66, c = rc - (rc / 66) * 66;
  __bf16* dst = xpad + (long)t * 512;
  if (r == 0 || r == 65 || c == 0 || c == 65) {
    const f32x4 z = {0.f, 0.f, 0.f, 0.f};
#pragma unroll 4
    for (int j = 0; j < 64; ++j) *(f32x4*)(dst + j * 8) = z;
  } else {
    const float* src = imgs + ((long)b << 21) + ((r - 1) << 6) + (c - 1);
    for (int j = 0; j < 64; ++j) {
      bf16x8 v;
#pragma unroll
      for (int q = 0; q < 8; ++q) v[q] = (__bf16)src[(long)(j * 8 + q) << 12];
      *(bf16x8*)(dst + j * 8) = v;
    }
  }
}

// Conv: block = 128 out-chans x 128 px (4h x 32w), 4 waves (2x2 of 64x64).
// Phase = (icb64, half, kx): stage 3-tap x 32-ch A-slab (24.6KB) [+ X at
// first phase of icb]; compute bfr[4][2] once, sweep ky=0..2 (48 MFMA).
// LDS: sX 28672 + sA3 24576 = 53248 B -> 3 blocks/CU.
__global__ __launch_bounds__(256, 3) void k_conv(const __bf16* __restrict__ xpad,
                                                 const __bf16* __restrict__ wt,
                                                 const float* __restrict__ bias,
                                                 float* __restrict__ out) {
  __shared__ __attribute__((aligned(16))) __bf16 sX[224 * 64];      // 204 px used
  __shared__ __attribute__((aligned(16))) __bf16 sA3[3 * 128 * 32]; // 3-tap K=32

  const int tid = threadIdx.x;
  const int lane = tid & 63;
  const int wid = tid >> 6;
  const int wr = wid >> 1, wc = wid & 1;
  const int l15 = lane & 15, lq = lane >> 4;

  const int bid = blockIdx.x;
  const int b = bid >> 7;          // 128 blocks / batch
  const int r7 = bid & 127;
  const int o0 = (r7 >> 5) << 7;   // 4 o-tiles of 128
  const int st = r7 & 31;          // 32 spatial tiles
  const int h0 = (st >> 1) << 2;   // 16 h-tiles * 4 rows
  const int w0 = (st & 1) << 5;    // 2 w-tiles * 32 cols

  // X staging: 1792 16B slots; slot s -> px p=s>>3, holds chunk (s&7)^(p&7).
  const __bf16* xg[7];
#pragma unroll
  for (int it = 0; it < 7; ++it) {
    int s = it * 256 + tid;
    int p = s >> 3;
    int pp = (p < 204) ? p : 0;  // pad slots read dummy, never consumed
    int j = (s & 7) ^ (pp & 7);
    int lr = pp / 34, lc = pp - lr * 34;
    xg[it] = xpad + ((long)((b * 66 + h0 + lr) * 66) + (w0 + lc)) * 512 + j * 8;
  }
  // A staging (K=32 slab): per it (0..5): tap=it>>1, rowgrp=it&1 (64 rows).
  // Thread: row64=tid>>2, j=tid&3, swizzled j'=j^((tid>>3)&3).
  // src elem = (kx*3+tap)*262144 + rowgrp*32768 + abase + ic64 + half*32.
  const int abase = ((o0 + (tid >> 2)) << 9) + (((tid & 3) ^ ((tid >> 3) & 3)) << 3);
  const __bf16* wtb = wt + (long)b * 2359296;

  f32x4 acc[4][4];
  const f32x4 zero4 = {0.f, 0.f, 0.f, 0.f};
#pragma unroll
  for (int m = 0; m < 4; ++m)
#pragma unroll
    for (int n = 0; n < 4; ++n) acc[m][n] = zero4;

  const int arowbase = (wr << 6) + l15;                 // A o-row for m=0
  const int csA = (lq ^ ((l15 >> 1) & 3)) << 3;         // A chunk swizzle (elems)
  const int rbase = wc << 1;                            // wave's first halo row

  bool first = true;
  for (int icb = 0; icb < 8; ++icb) {
    const int ic = icb << 6;
#pragma unroll
    for (int hf = 0; hf < 2; ++hf) {
#pragma unroll
      for (int kx = 0; kx < 3; ++kx) {
        if (!first) __syncthreads();  // prior compute done; safe to overwrite
        first = false;
        if (hf == 0 && kx == 0) {
#pragma unroll
          for (int it = 0; it < 7; ++it)
            async16(xg[it] + ic, (char*)sX + it * 4096 + (wid << 10));
        }
        {
          const __bf16* wa = wtb + abase + ic + (hf << 5);
#pragma unroll
          for (int it = 0; it < 6; ++it)
            async16(wa + (kx * 3 + (it >> 1)) * 262144 + (it & 1) * 32768,
                    (char*)sA3 + it * 4096 + (wid << 10));
        }
        __syncthreads();  // compiler drains vmcnt(0) before s_barrier
        // ---- compute: 48 MFMA from sA3 + sX ----
        const int jb = (hf << 2) | lq;  // sX chunk for this half
        bf16x8 bfr[4][2];
#pragma unroll
        for (int r = 0; r < 4; ++r)
#pragma unroll
          for (int c = 0; c < 2; ++c) {
            int p = (rbase + r) * 34 + (c << 4) + l15 + kx;
            bfr[r][c] = *(const bf16x8*)&sX[(p << 6) + ((jb ^ (p & 7)) << 3)];
          }
#pragma unroll
        for (int ky = 0; ky < 3; ++ky) {
          const __bf16* sAb = sA3 + ky * 4096;
          bf16x8 af[4];
#pragma unroll
          for (int m = 0; m < 4; ++m)
            af[m] = *(const bf16x8*)&sAb[((arowbase + (m << 4)) << 5) + csA];
#pragma unroll
          for (int m = 0; m < 4; ++m)
#pragma unroll
            for (int q = 0; q < 2; ++q)
#pragma unroll
              for (int c = 0; c < 2; ++c)
                acc[m][(q << 1) + c] = __builtin_amdgcn_mfma_f32_16x16x32_bf16(
                    af[m], bfr[q + ky][c], acc[m][(q << 1) + c], 0, 0, 0);
        }
      }
    }
  }

  // Epilogue: C/D col=lane&15 (pixel), row=(lane>>4)*4+q (out chan).
  // n = q*2 + c: pixel id nn = wc*64 + n*16 + l15 (row nn>>5, col nn&31).
  float* outb = out + ((long)b << 21);
#pragma unroll
  for (int m = 0; m < 4; ++m) {
    int ob = o0 + (wr << 6) + (m << 4) + (lq << 2);
#pragma unroll
    for (int n = 0; n < 4; ++n) {
      int nn = (wc << 6) + (n << 4) + l15;
      int h = h0 + (nn >> 5), w = w0 + (nn & 31);
#pragma unroll
      for (int q = 0; q < 4; ++q) {
        int o = ob + q;
        outb[((long)o << 12) + (h << 6) + w] = acc[m][n][q] + bias[o];
      }
    }
  }
}

extern "C" void kernel_launch(void* const* d_in, const int* in_sizes, int n_in,
                              void* d_out, int out_size, void* d_ws, size_t ws_size,
                              hipStream_t stream) {
  const float* imgs = (const float*)d_in[0];
  const float* w_embs = (const float*)d_in[1];
  const float* cw = (const float*)d_in[2];
  const float* bias = (const float*)d_in[3];
  const float* style_W = (const float*)d_in[4];
  const float* style_b = (const float*)d_in[5];
  float* out = (float*)d_out;

  char* ws = (char*)d_ws;
  float* style = (float*)(ws);                          // 32 KB
  float* rnorm = (float*)(ws + (32 << 10));             // 32 KB
  float* wsq = (float*)(ws + (64 << 10));               // 1 MB
  __bf16* wt = (__bf16*)(ws + (64 << 10) + (1 << 20));  // 75,497,472 B
  __bf16* xpad = (__bf16*)(ws + (64 << 10) + (1 << 20) + 75497472);  // 71,368,704 B
  size_t need = (size_t)(64 << 10) + (1 << 20) + 75497472ull + 71368704ull;
  if (ws_size < need) return;  // leaves d_out poisoned -> visible failure mode

  k_style<<<2048, 256, 0, stream>>>(w_embs, style_W, style_b, style);
  k_wsq<<<1024, 256, 0, stream>>>(cw, wsq);
  k_rnorm<<<2048, 256, 0, stream>>>(style, wsq, rnorm);
  k_wt<<<16384, 256, 0, stream>>>(cw, style, rnorm, wt);
  k_xpad<<<273, 256, 0, stream>>>(imgs, xpad);
  k_conv<<<2048, 256, 0, stream>>>(xpad, wt, bias, out);
}

// Round 10
// 369.142 us; speedup vs baseline: 1.0592x; 1.0592x over previous
//
#include <hip/hip_runtime.h>

// ModulatedConv2d: B=16, C=512->512, 3x3 SAME, per-sample demodulated weights.
// R9: wave tile 64o x 128px (acc[4][8], 128 AGPR) - LDS reads/FLOP -40%
// (1/64+1/128 vs 1/64+1/64). Block = 128o x 256px (8h x 32w), 4 waves 2x2.
// Ledger: LDS-bytes levers always paid (R2 -25%, R7 -8%); occupancy lever
// refuted (R8: 3 blk == 2 blk); pipelining refuted (R4). So: plain-barrier
// R8 schedule, phases=(icb,hf,kx)=48, A-slab K=32 3-tap (R8 verbatim),
// X = R3's proven 340px staging (11 async16 + clamp), K=64 with hf read
// split. LDS 45.1+24.6=69.6KB -> 2 blocks/CU. Spill watch: arch target
// <=120 VGPR (R3 failed here with fat staging state; R8 machinery is lean).

typedef __bf16 bf16x8 __attribute__((ext_vector_type(8)));
typedef float f32x4 __attribute__((ext_vector_type(4)));

__device__ __forceinline__ void async16(const void* g, void* s) {
  __builtin_amdgcn_global_load_lds((const __attribute__((address_space(1))) void*)g,
                                   (__attribute__((address_space(3))) void*)s, 16, 0, 0);
}

// style[b][i] = dot(w_embs[b,:], style_W[i,:]) + style_b[i] + 1
__global__ __launch_bounds__(256) void k_style(const float* __restrict__ we,
                                               const float* __restrict__ sW,
                                               const float* __restrict__ sb,
                                               float* __restrict__ style) {
  int lane = threadIdx.x & 63, wid = threadIdx.x >> 6;
  int b = blockIdx.x >> 7;
  int i = ((blockIdx.x & 127) << 2) + wid;
  const float* wer = we + b * 512;
  const float* swr = sW + i * 512;
  float acc = 0.f;
  for (int d = lane; d < 512; d += 64) acc += wer[d] * swr[d];
#pragma unroll
  for (int off = 32; off; off >>= 1) acc += __shfl_xor(acc, off);
  if (lane == 0) style[b * 512 + i] = acc + sb[i] + 1.0f;
}

// wsq[o][i] = sum_k cw[o][i][k]^2
__global__ __launch_bounds__(256) void k_wsq(const float* __restrict__ cw,
                                             float* __restrict__ wsq) {
  int t = blockIdx.x * 256 + threadIdx.x;  // o*512+i
  const float* p = cw + (long)t * 9;
  float s = 0.f;
#pragma unroll
  for (int k = 0; k < 9; ++k) s += p[k] * p[k];
  wsq[t] = s;
}

// rnorm[b][o] = rsqrt(sum_i style[b,i]^2 * wsq[o,i])
__global__ __launch_bounds__(256) void k_rnorm(const float* __restrict__ style,
                                               const float* __restrict__ wsq,
                                               float* __restrict__ rnorm) {
  int lane = threadIdx.x & 63, wid = threadIdx.x >> 6;
  int idx = blockIdx.x * 4 + wid;  // b*512 + o
  int b = idx >> 9, o = idx & 511;
  float acc = 0.f;
  for (int i = lane; i < 512; i += 64) {
    float s = style[(b << 9) + i];
    acc += s * s * wsq[(o << 9) + i];
  }
#pragma unroll
  for (int off = 32; off; off >>= 1) acc += __shfl_xor(acc, off);
  if (lane == 0) rnorm[idx] = rsqrtf(acc);
}

// wt[b][t'][o][i], t' = kx*3 + ky (kx-MAJOR so a (ky=0..2,kx) slab is
// contiguous): value = cw[o][i][ky*3+kx] * style[b][i] * rnorm[b][o].
__global__ __launch_bounds__(256) void k_wt(const float* __restrict__ cw,
                                            const float* __restrict__ style,
                                            const float* __restrict__ rnorm,
                                            __bf16* __restrict__ wt) {
  int t = blockIdx.x * 256 + threadIdx.x;  // b*262144 + o*512 + i
  int b = t >> 18;
  int oi = t & 262143;
  int o = oi >> 9, i = oi & 511;
  float sc = style[(b << 9) + i] * rnorm[(b << 9) + o];
  const float* p = cw + (long)oi * 9;
#pragma unroll
  for (int k = 0; k < 9; ++k) {  // k = ky*3+kx  ->  t' = kx*3+ky
    int tp = (k % 3) * 3 + k / 3;
    wt[((long)(b * 9 + tp) << 18) + ((long)o << 9) + i] = (__bf16)(p[k] * sc);
  }
}

// xpad[b][r][c][i] (r,c in [0,66)) = bf16(imgs[b][i][r-1][c-1]), zero border.
__global__ __launch_bounds__(256) void k_xpad(const float* __restrict__ imgs,
                                              __bf16* __restrict__ xpad) {
  int t = blockIdx.x * 256 + threadIdx.x;  // b*4356 + r*66 + c
  if (t >= 16 * 4356) return;
  int b = t / 4356;
  int rc = t - b * 4356;
  int r = rc / 66, c = rc - (rc / 66) * 66;
  __bf16* dst = xpad + (long)t * 512;
  if (r == 0 || r == 65 || c == 0 || c == 65) {
    const f32x4 z = {0.f, 0.f, 0.f, 0.f};
#pragma unroll 4
    for (int j = 0; j < 64; ++j) *(f32x4*)(dst + j * 8) = z;
  } else {
    const float* src = imgs + ((long)b << 21) + ((r - 1) << 6) + (c - 1);
    for (int j = 0; j < 64; ++j) {
      bf16x8 v;
#pragma unroll
      for (int q = 0; q < 8; ++q) v[q] = (__bf16)src[(long)(j * 8 + q) << 12];
      *(bf16x8*)(dst + j * 8) = v;
    }
  }
}

// Conv: block = 128 o x 256 px (8h x 32w), 4 waves = 2(o) x 2(px), wave
// tile 64o x 128px, acc[4][8]. Phase = (icb64, hf, kx): stage 3-tap x 32ch
// A-slab (24.6KB) [+ X(340px,K=64) at first phase of icb]; compute
// bfr[6][2] once, sweep ky=0..2 with af[4] -> 96 MFMA/phase/wave.
// LDS: sX 45056 + sA3 24576 = 69632 B -> 2 blocks/CU.
__global__ __launch_bounds__(256, 2) void k_conv(const __bf16* __restrict__ xpad,
                                                 const __bf16* __restrict__ wt,
                                                 const float* __restrict__ bias,
                                                 float* __restrict__ out) {
  __shared__ __attribute__((aligned(16))) __bf16 sX[2816 * 8];      // 340 px used
  __shared__ __attribute__((aligned(16))) __bf16 sA3[3 * 128 * 32]; // 3-tap K=32

  const int tid = threadIdx.x;
  const int lane = tid & 63;
  const int wid = tid >> 6;
  const int wr = wid >> 1, wp = wid & 1;
  const int l15 = lane & 15, lq = lane >> 4;

  const int bid = blockIdx.x;
  const int b = bid >> 6;          // 64 blocks / batch
  const int r6 = bid & 63;
  const int o0 = (r6 >> 4) << 7;   // 4 o-tiles of 128
  const int st = r6 & 15;          // 16 spatial tiles
  const int h0 = (st >> 1) << 3;   // 8 h-tiles * 8 rows
  const int w0 = (st & 1) << 5;    // 2 w-tiles * 32 cols
  const int b66 = b * 66;

  // X staging (R3-proven 340px geometry): slot s=it*256+tid (clamped 2719),
  // px p=s>>3, holds chunk j=(s&7)^(p&7); LDS pad slots 2720..2815 unused.
  const __bf16* xg[11];
#pragma unroll
  for (int it = 0; it < 11; ++it) {
    int s = it * 256 + tid;
    if (s > 2719) s = 2719;
    int p = s >> 3;
    int j = (s & 7) ^ (p & 7);
    int lr = p / 34, lc = p - (p / 34) * 34;
    xg[it] = xpad + ((long)((b66 + h0 + lr) * 66) + (w0 + lc)) * 512 + j * 8;
  }
  // A staging (R8-verbatim K=32 slab): it 0..5: tap=it>>1, rowgrp=it&1.
  const int abase = ((o0 + (tid >> 2)) << 9) + (((tid & 3) ^ ((tid >> 3) & 3)) << 3);
  const __bf16* wtb = wt + (long)b * 2359296;

  f32x4 acc[4][8];
  const f32x4 zero4 = {0.f, 0.f, 0.f, 0.f};
#pragma unroll
  for (int m = 0; m < 4; ++m)
#pragma unroll
    for (int n = 0; n < 8; ++n) acc[m][n] = zero4;

  const int arowbase = (wr << 6) + l15;          // A o-row for m=0
  const int csA = (lq ^ ((l15 >> 1) & 3)) << 3;  // A chunk swizzle (elems)
  const int rbase = wp << 2;                     // wave's first halo row

  bool first = true;
  for (int icb = 0; icb < 8; ++icb) {
    const int ic = icb << 6;
#pragma unroll
    for (int hf = 0; hf < 2; ++hf) {
#pragma unroll
      for (int kx = 0; kx < 3; ++kx) {
        if (!first) __syncthreads();  // prior compute done; safe to overwrite
        first = false;
        if (hf == 0 && kx == 0) {
#pragma unroll
          for (int it = 0; it < 11; ++it)
            async16(xg[it] + ic, (char*)sX + it * 4096 + (wid << 10));
        }
        {
          const __bf16* wa = wtb + abase + ic + (hf << 5);
#pragma unroll
          for (int it = 0; it < 6; ++it)
            async16(wa + (kx * 3 + (it >> 1)) * 262144 + (it & 1) * 32768,
                    (char*)sA3 + it * 4096 + (wid << 10));
        }
        __syncthreads();  // compiler drains vmcnt(0) before s_barrier
        // ---- compute: 96 MFMA from sA3 + sX ----
        const int jb = (hf << 2) | lq;  // sX chunk for this half
        bf16x8 bfr[6][2];
#pragma unroll
        for (int r = 0; r < 6; ++r)
#pragma unroll
          for (int c = 0; c < 2; ++c) {
            int p = (rbase + r) * 34 + (c << 4) + l15 + kx;
            bfr[r][c] = *(const bf16x8*)&sX[(p << 6) + ((jb ^ (p & 7)) << 3)];
          }
#pragma unroll
        for (int ky = 0; ky < 3; ++ky) {
          const __bf16* sAb = sA3 + ky * 4096;
          bf16x8 af[4];
#pragma unroll
          for (int m = 0; m < 4; ++m)
            af[m] = *(const bf16x8*)&sAb[((arowbase + (m << 4)) << 5) + csA];
#pragma unroll
          for (int m = 0; m < 4; ++m)
#pragma unroll
            for (int n = 0; n < 8; ++n)
              acc[m][n] = __builtin_amdgcn_mfma_f32_16x16x32_bf16(
                  af[m], bfr[(n >> 1) + ky][n & 1], acc[m][n], 0, 0, 0);
        }
      }
    }
  }

  // Epilogue: C/D col=lane&15 (pixel), row=(lane>>4)*4+q (out chan).
  // pixel id = wp*128 + n*16 + l15 -> h = h0 + pid>>5, w = w0 + (pid&31).
  float* outb = out + ((long)b << 21);
#pragma unroll
  for (int m = 0; m < 4; ++m) {
    int ob = o0 + (wr << 6) + (m << 4) + (lq << 2);
#pragma unroll
    for (int n = 0; n < 8; ++n) {
      int pid = (wp << 7) + (n << 4) + l15;
      int h = h0 + (pid >> 5), w = w0 + (pid & 31);
#pragma unroll
      for (int q = 0; q < 4; ++q) {
        int o = ob + q;
        outb[((long)o << 12) + (h << 6) + w] = acc[m][n][q] + bias[o];
      }
    }
  }
}

extern "C" void kernel_launch(void* const* d_in, const int* in_sizes, int n_in,
                              void* d_out, int out_size, void* d_ws, size_t ws_size,
                              hipStream_t stream) {
  const float* imgs = (const float*)d_in[0];
  const float* w_embs = (const float*)d_in[1];
  const float* cw = (const float*)d_in[2];
  const float* bias = (const float*)d_in[3];
  const float* style_W = (const float*)d_in[4];
  const float* style_b = (const float*)d_in[5];
  float* out = (float*)d_out;

  char* ws = (char*)d_ws;
  float* style = (float*)(ws);                          // 32 KB
  float* rnorm = (float*)(ws + (32 << 10));             // 32 KB
  float* wsq = (float*)(ws + (64 << 10));               // 1 MB
  __bf16* wt = (__bf16*)(ws + (64 << 10) + (1 << 20));  // 75,497,472 B
  __bf16* xpad = (__bf16*)(ws + (64 << 10) + (1 << 20) + 75497472);  // 71,368,704 B
  size_t need = (size_t)(64 << 10) + (1 << 20) + 75497472ull + 71368704ull;
  if (ws_size < need) return;  // leaves d_out poisoned -> visible failure mode

  k_style<<<2048, 256, 0, stream>>>(w_embs, style_W, style_b, style);
  k_wsq<<<1024, 256, 0, stream>>>(cw, wsq);
  k_rnorm<<<2048, 256, 0, stream>>>(style, wsq, rnorm);
  k_wt<<<16384, 256, 0, stream>>>(cw, style, rnorm, wt);
  k_xpad<<<273, 256, 0, stream>>>(imgs, xpad);
  k_conv<<<1024, 256, 0, stream>>>(xpad, wt, bias, out);
}